// Round 6
// baseline (526.821 us; speedup 1.0000x reference)
//
#include <hip/hip_runtime.h>
#include <math.h>

#define DDIM 512
#define NNN  4096
#define KKK  2048
#define MMM  32768          // 8*4096 queries

#define TMQ  128            // queries per block (main)
#define TNC  256            // codes per k-tile (main)
#define BK   64             // d per staging round (main)
#define KSPLIT 4
#define KHALF (KKK/KSPLIT)  // 512
#define NKT  (KHALF/TNC)    // 2
#define NDR  (DDIM/BK)      // 8
#define TAU  0.25f          // flag margin for exact re-resolve (passed absmax=0 twice)
#define CAPF 4096           // flagged-query capacity

// d_out scratch layout (floats) inside the quantize region [0, 16777216),
// fully overwritten by the final gather:
#define XH_OFF   0                      // x^T bf16 [m][d]: 8388608 floats
#define EH_OFF   8388608                // embed bf16 [k][d]: 524288 floats
#define PART_OFF (EH_OFF + 524288)      // per (q,ks) triple: MMM*KSPLIT*4 = 524288 floats
#define XF_OFF   (PART_OFF + 524288)    // compact fp32 x [slot][d]: CAPF*512 = 2097152
#define KEY_OFF  (XF_OFF + 2097152)     // CAPF u64 keys (byte off %8 == 0)
#define LIST_OFF (KEY_OFF + 8192)       // flagged-query list (ints)
#define CNT_OFF  (LIST_OFF + CAPF)      // atomic counter (int)
#define IDX_OFF  ((size_t)MMM * DDIM)   // output 1: indices as float

typedef short short8v __attribute__((ext_vector_type(8)));
typedef float f32x4   __attribute__((ext_vector_type(4)));

__device__ inline unsigned short f2bf(float f) {          // fp32 -> bf16 RNE
  unsigned u = __float_as_uint(f);
  u = u + 0x7FFFu + ((u >> 16) & 1u);
  return (unsigned short)(u >> 16);
}

// async global->LDS, 16B per lane; LDS dest = uniform base + lane*16
__device__ inline void gl_lds16(const short* g, short* l) {
  __builtin_amdgcn_global_load_lds(
      (const __attribute__((address_space(1))) unsigned int*)g,
      (__attribute__((address_space(3))) unsigned int*)l, 16, 0, 0);
}

__device__ inline unsigned mono(float f) {   // monotone float -> uint
  unsigned u = __float_as_uint(f);
  return (u & 0x80000000u) ? ~u : (u | 0x80000000u);
}

// XOR-swizzled frag-read short-index into a [rows][64-short] tile:
// physical 16B-quad = (dk>>3) ^ (row&7); row stride 128 B would otherwise be
// 16-way conflicted (0 mod 32 banks). Verified: conflicts 1.9e7 -> 0 (R5).
__device__ inline int fswz(int row, int dk) {
  return row*64 + ((((dk >> 3) ^ (row & 7)) << 3));
}

// ---- fused: x transpose->bf16 plane; first 512 blocks also do embed->bf16 +
//      halfe2 + counter/key init -----------------------------------------------
__global__ __launch_bounds__(256)
void conv_x(const float* __restrict__ x, const float* __restrict__ embed,
            float* __restrict__ halfe2, float* __restrict__ out) {
  __shared__ float xt[64][65];          // +1 pad: conflict-free column reads
  const int t  = threadIdx.x;
  const int gid = blockIdx.x * 256 + t;
  if (gid == 0) *(int*)&out[CNT_OFF] = 0;
  if (gid < CAPF) ((unsigned long long*)&out[KEY_OFF])[gid] = ~0ull;

  const int nt = blockIdx.x & 63, dt = (blockIdx.x >> 6) & 7, b = blockIdx.x >> 9;
  const int n0 = nt * 64, d0 = dt * 64;
  const float* xb = x + ((size_t)b * DDIM + d0) * NNN + n0;
  #pragma unroll
  for (int i = 0; i < 4; ++i) {
    const int fid = t + 256*i;
    const int dl = fid >> 4, n4 = (fid & 15) * 4;
    const float4 v = *(const float4*)&xb[(size_t)dl * NNN + n4];
    xt[dl][n4+0] = v.x; xt[dl][n4+1] = v.y; xt[dl][n4+2] = v.z; xt[dl][n4+3] = v.w;
  }
  __syncthreads();
  short* xh = (short*)&out[XH_OFF];
  const int m0 = b * NNN + n0;
  #pragma unroll
  for (int i = 0; i < 2; ++i) {
    const int id = t + 256*i;
    const int m = id >> 3, ch = (id & 7) * 8;
    short8v p;
    #pragma unroll
    for (int j = 0; j < 8; ++j) p[j] = (short)f2bf(xt[ch + j][m]);
    *(short8v*)&xh[(size_t)(m0 + m) * DDIM + d0 + ch] = p;
  }

  // fused conv_e: blocks 0..511 each convert 4 embed rows + halfe2
  if (blockIdx.x < KKK/4) {
    const int row  = blockIdx.x * 4 + (t >> 6);
    const int lane = t & 63;
    const float* e = embed + (size_t)row * DDIM;
    short* eh = (short*)&out[EH_OFF];
    const float4 v0 = *(const float4*)&e[lane*8];
    const float4 v1 = *(const float4*)&e[lane*8 + 4];
    const float vv[8] = {v0.x,v0.y,v0.z,v0.w,v1.x,v1.y,v1.z,v1.w};
    float s = 0.f;
    short8v p;
    #pragma unroll
    for (int i = 0; i < 8; ++i) { s = fmaf(vv[i], vv[i], s); p[i] = (short)f2bf(vv[i]); }
    *(short8v*)&eh[(size_t)row * DDIM + lane*8] = p;
    #pragma unroll
    for (int off = 32; off >= 1; off >>= 1) s += __shfl_xor(s, off, 64);
    if (lane == 0) halfe2[row] = 0.5f * s;
  }
}

// ---- main: pure bf16 MFMA GEMM + deferred fused argmin ---------------------
// score[q][k] = 0.5*||e_k||^2 - <x_q, e_k>
__global__ __launch_bounds__(256, 3)
void vq_main(const float* __restrict__ halfe2, float* __restrict__ out) {
  __shared__ __align__(16) short lds[(TMQ + TNC) * BK];   // 48 KB -> 3 blocks/CU
  short* xs = lds;              // [128 rows][64 d], XOR-swizzled quads
  short* es = lds + TMQ*BK;     // [256 rows][64 d], XOR-swizzled quads
  const short* xh = (const short*)&out[XH_OFF];
  const short* eh = (const short*)&out[EH_OFF];

  const int t  = threadIdx.x;
  const int mb = blockIdx.x >> 2, ks = blockIdx.x & 3;
  const int q0 = mb * TMQ;
  const int kbase = ks * KHALF;
  const int w = t >> 6, lane = t & 63;
  const int mw = (w >> 1) * 64, nw = (w & 1) * 128;   // wave 64x128 sub-tile
  const int l15 = lane & 15, lg = lane >> 4;
  const int c0 = w * 12;
  const int lrow = lane >> 3;                          // staging row within chunk
  const int scol = (((lane & 7) ^ lrow) << 3);         // swizzled source quad

  // deferred per-lane running (best, idx, 2nd-best) for 16 queries/lane
  float rv1[16], rv2[16]; int ri1[16];
  #pragma unroll
  for (int i = 0; i < 16; ++i) { rv1[i] = INFINITY; rv2[i] = INFINITY; ri1[i] = 0x7FFFFFFF; }

  for (int kt = 0; kt < NKT; ++kt) {
    const int kb = kbase + kt * TNC;
    f32x4 acc[4][8];
    #pragma unroll
    for (int mi = 0; mi < 4; ++mi)
      #pragma unroll
      for (int ni = 0; ni < 8; ++ni) acc[mi][ni] = (f32x4){0.f,0.f,0.f,0.f};

    for (int dr = 0; dr < NDR; ++dr) {
      const int d0 = dr * BK;
      __syncthreads();
      // stage 48 KB via global_load_lds; swizzle folded into source column
      #pragma unroll
      for (int j = 0; j < 12; ++j) {
        const int c = c0 + j;
        if (c < 16) {
          gl_lds16(xh + (size_t)(q0 + c*8 + lrow) * DDIM + d0 + scol, &lds[c * 512]);
        } else {
          gl_lds16(eh + (size_t)(kb + (c-16)*8 + lrow) * DDIM + d0 + scol, &lds[c * 512]);
        }
      }
      __syncthreads();
      #pragma unroll
      for (int kk = 0; kk < 2; ++kk) {
        const int dk = kk*32 + lg*8;
        short8v bfr[8];
        #pragma unroll
        for (int ni = 0; ni < 8; ++ni)
          bfr[ni] = *(const short8v*)&es[fswz(nw + ni*16 + l15, dk)];
        #pragma unroll
        for (int mi = 0; mi < 4; ++mi) {
          const short8v a = *(const short8v*)&xs[fswz(mw + mi*16 + l15, dk)];
          #pragma unroll
          for (int ni = 0; ni < 8; ++ni)
            acc[mi][ni] = __builtin_amdgcn_mfma_f32_16x16x32_bf16(a, bfr[ni], acc[mi][ni], 0,0,0);
        }
      }
    }

    // per-k-tile: per-lane tournament only; candidate indices strictly ascend
    float he[8];
    #pragma unroll
    for (int ni = 0; ni < 8; ++ni) he[ni] = halfe2[kb + nw + ni*16 + l15];
    #pragma unroll
    for (int mi = 0; mi < 4; ++mi) {
      #pragma unroll
      for (int r = 0; r < 4; ++r) {
        const int e_ = mi*4 + r;
        #pragma unroll
        for (int ni = 0; ni < 8; ++ni) {
          const float sc = he[ni] - acc[mi][ni][r];
          if (sc < rv1[e_]) { rv2[e_] = rv1[e_]; rv1[e_] = sc; ri1[e_] = kb + nw + ni*16 + l15; }
          else rv2[e_] = fminf(rv2[e_], sc);
        }
      }
    }
  }

  // once: cross-lane merge over the 16 code-columns
  #pragma unroll
  for (int e_ = 0; e_ < 16; ++e_) {
    float v1 = rv1[e_], v2 = rv2[e_]; int i1 = ri1[e_];
    #pragma unroll
    for (int off = 1; off < 16; off <<= 1) {
      const float ov1 = __shfl_xor(v1, off, 64);
      const int   oi1 = __shfl_xor(i1, off, 64);
      const float ov2 = __shfl_xor(v2, off, 64);
      if (ov1 < v1 || (ov1 == v1 && oi1 < i1)) { v2 = fminf(v1, ov2); v1 = ov1; i1 = oi1; }
      else v2 = fminf(v2, ov1);
    }
    rv1[e_] = v1; rv2[e_] = v2; ri1[e_] = i1;
  }

  // merge the two code-half waves (w&1) per query via LDS; store partial triple
  __syncthreads();
  float* mbuf = (float*)lds;   // [128 q][2 halves][3]
  if (l15 == 0) {
    #pragma unroll
    for (int mi = 0; mi < 4; ++mi)
      #pragma unroll
      for (int r = 0; r < 4; ++r) {
        const int ql = mw + mi*16 + lg*4 + r;
        const int slot = (ql*2 + (w & 1))*3;
        const int e_ = mi*4 + r;
        mbuf[slot+0] = rv1[e_];
        mbuf[slot+1] = __int_as_float(ri1[e_]);
        mbuf[slot+2] = rv2[e_];
      }
  }
  __syncthreads();
  if (t < TMQ) {
    const float a1 = mbuf[t*6+0]; const int ai = __float_as_int(mbuf[t*6+1]); const float a2 = mbuf[t*6+2];
    const float b1 = mbuf[t*6+3]; const int bi = __float_as_int(mbuf[t*6+4]); const float b2 = mbuf[t*6+5];
    float v1, v2; int i1;
    if (b1 < a1 || (b1 == a1 && bi < ai)) { v1 = b1; i1 = bi; v2 = fminf(a1, b2); }
    else                                  { v1 = a1; i1 = ai; v2 = fminf(a2, b1); }
    f32x4 st = {v1, (float)i1, v2, 0.f};
    *(f32x4*)&out[PART_OFF + ((size_t)(q0 + t)*KSPLIT + ks)*4] = st;
  }
}

// ---- merge K-split partials; write index; flag ambiguous queries -----------
__global__ void vq_merge(float* __restrict__ out) {
  const int q = blockIdx.x * 256 + threadIdx.x;
  float v1 = INFINITY, v2 = INFINITY; int i1 = 0x7FFFFFFF;
  #pragma unroll
  for (int ks = 0; ks < KSPLIT; ++ks) {   // ks ascending = code ranges ascending
    const f32x4 p = *(const f32x4*)&out[PART_OFF + ((size_t)q*KSPLIT + ks)*4];
    const float b1 = p[0]; const int bi = (int)p[1]; const float b2 = p[2];
    if (b1 < v1 || (b1 == v1 && bi < i1)) { v2 = fminf(v1, b2); v1 = b1; i1 = bi; }
    else v2 = fminf(v2, b1);
  }
  out[IDX_OFF + q] = (float)i1;
  if (v2 - v1 < TAU) {
    const int pos = atomicAdd((int*)&out[CNT_OFF], 1);
    if (pos < CAPF) ((int*)&out[LIST_OFF])[pos] = q;
  }
}

// ---- prep: compact flagged x rows into fp32 plane XF[slot][d] --------------
__global__ __launch_bounds__(256)
void vq_prep(const float* __restrict__ x, float* __restrict__ out) {
  const int nf0 = *(const int*)&out[CNT_OFF];
  const int nf  = nf0 < CAPF ? nf0 : CAPF;
  const int* list = (const int*)&out[LIST_OFF];
  float* XF = &out[XF_OFF];
  const int wid  = (blockIdx.x * 256 + threadIdx.x) >> 6;   // 1024 waves
  const int lane = threadIdx.x & 63;
  for (int s = wid; s < nf; s += 1024) {
    const int q = list[s];
    const int b = q >> 12, n = q & (NNN - 1);
    const float* xb = x + (size_t)b * DDIM * NNN + n;
    #pragma unroll
    for (int j = 0; j < 8; ++j) {
      const int d = lane + 64*j;
      XF[(size_t)s * DDIM + d] = xb[(size_t)d * NNN];
    }
  }
}

// ---- refine: exact fp32 microtile GEMM over flagged slots ------------------
__global__ __launch_bounds__(256, 2)
void vq_refine(const float* __restrict__ embed, const float* __restrict__ halfe2,
               float* __restrict__ out) {
  const int nf0 = *(const int*)&out[CNT_OFF];
  const int nf  = nf0 < CAPF ? nf0 : CAPF;
  const int s0  = blockIdx.y * 64;
  if (s0 >= nf) return;
  __shared__ float xs[32][68];   // stride 68: float4-aligned, <=4-way stage writes
  __shared__ float es[32][132];
  const int t = threadIdx.x, tx = t & 15, ty = t >> 4;
  const int kb = blockIdx.x * 128;
  const float* XF = &out[XF_OFF];
  unsigned long long* keys = (unsigned long long*)&out[KEY_OFF];

  float acc[4][8];
  #pragma unroll
  for (int i = 0; i < 4; ++i)
    #pragma unroll
    for (int j = 0; j < 8; ++j) acc[i][j] = 0.f;

  for (int dc = 0; dc < 16; ++dc) {
    __syncthreads();
    #pragma unroll
    for (int i = 0; i < 2; ++i) {        // xs[d][m] <- XF[s0+m][.] row float4 reads
      const int l = t + 256*i;
      const int m = l >> 3, f = l & 7;
      const float4 v = *(const float4*)&XF[(size_t)(s0 + m) * DDIM + dc*32 + 4*f];
      xs[4*f+0][m] = v.x; xs[4*f+1][m] = v.y; xs[4*f+2][m] = v.z; xs[4*f+3][m] = v.w;
    }
    #pragma unroll
    for (int i = 0; i < 4; ++i) {        // es[d][k] <- embed rows (float4)
      const int l = t + 256*i;
      const int k = l >> 3, f = l & 7;
      const float4 v = *(const float4*)&embed[(size_t)(kb + k)*DDIM + dc*32 + 4*f];
      es[4*f+0][k] = v.x; es[4*f+1][k] = v.y; es[4*f+2][k] = v.z; es[4*f+3][k] = v.w;
    }
    __syncthreads();
    #pragma unroll
    for (int d = 0; d < 32; ++d) {       // sequential d: deterministic sum order
      const float4 a4 = *(const float4*)&xs[d][ty*4];
      const float4 b0 = *(const float4*)&es[d][tx*4];
      const float4 b1 = *(const float4*)&es[d][64 + tx*4];
      const float a[4]  = {a4.x, a4.y, a4.z, a4.w};
      const float bb[8] = {b0.x, b0.y, b0.z, b0.w, b1.x, b1.y, b1.z, b1.w};
      #pragma unroll
      for (int i = 0; i < 4; ++i)
        #pragma unroll
        for (int j = 0; j < 8; ++j)
          acc[i][j] = fmaf(a[i], bb[j], acc[i][j]);
    }
  }

  const int kb0 = kb + tx*4, kb1 = kb + 64 + tx*4;
  const float4 h0 = *(const float4*)&halfe2[kb0];
  const float4 h1 = *(const float4*)&halfe2[kb1];
  const float hh[8] = {h0.x, h0.y, h0.z, h0.w, h1.x, h1.y, h1.z, h1.w};
  #pragma unroll
  for (int i = 0; i < 4; ++i) {
    float v = hh[0] - acc[i][0];
    int  vi = kb0;
    #pragma unroll
    for (int j = 1; j < 8; ++j) {
      const float w  = hh[j] - acc[i][j];
      const int   wk = (j < 4) ? (kb0 + j) : (kb1 + j - 4);
      if (w < v) { v = w; vi = wk; }     // ascending codes: strict < keeps first
    }
    #pragma unroll
    for (int off = 1; off < 16; off <<= 1) {
      const float ov = __shfl_xor(v, off, 64);
      const int   oi = __shfl_xor(vi, off, 64);
      if (ov < v || (ov == v && oi < vi)) { v = ov; vi = oi; }
    }
    if (tx == 0) {
      const unsigned long long key =
          ((unsigned long long)mono(v) << 32) | (unsigned)vi;
      atomicMin(&keys[s0 + ty*4 + i], key);
    }
  }
}

// ---- apply: decode refined keys back into IDX ------------------------------
__global__ void vq_apply(float* __restrict__ out) {
  const int slot = blockIdx.x * 256 + threadIdx.x;
  const int nf0 = *(const int*)&out[CNT_OFF];
  const int nf  = nf0 < CAPF ? nf0 : CAPF;
  if (slot >= nf) return;
  const int q = ((const int*)&out[LIST_OFF])[slot];
  const unsigned long long k = ((const unsigned long long*)&out[KEY_OFF])[slot];
  if (k != ~0ull) out[IDX_OFF + q] = (float)(unsigned)(k & 0xFFFFFFFFull);
}

// ---- gather quantize rows, float4 stores (overwrites all d_out scratch) ----
__global__ __launch_bounds__(256)
void vq_gather(const float* __restrict__ embed, float* __restrict__ out) {
  __shared__ int idx_s[128];
  const int t  = threadIdx.x;
  const int q0 = blockIdx.x * 128;
  const int b  = q0 >> 12, n0 = q0 & (NNN-1);
  if (t < 128) idx_s[t] = (int)out[IDX_OFF + q0 + t];
  __syncthreads();
  float* qb = out + (size_t)b * DDIM * NNN + n0;
  for (int j = 0; j < 64; ++j) {
    const int id = t + 256*j;
    const int d = id >> 5, n4 = (id & 31) * 4;
    float4 v;
    v.x = embed[(size_t)idx_s[n4+0]*DDIM + d];
    v.y = embed[(size_t)idx_s[n4+1]*DDIM + d];
    v.z = embed[(size_t)idx_s[n4+2]*DDIM + d];
    v.w = embed[(size_t)idx_s[n4+3]*DDIM + d];
    *(float4*)&qb[(size_t)d * NNN + n4] = v;
  }
}

extern "C" void kernel_launch(void* const* d_in, const int* in_sizes, int n_in,
                              void* d_out, int out_size, void* d_ws, size_t ws_size,
                              hipStream_t stream) {
  const float* x     = (const float*)d_in[0];   // [8, 512, 4096] fp32
  const float* embed = (const float*)d_in[1];   // [2048, 512] fp32
  float* out    = (float*)d_out;
  float* halfe2 = (float*)d_ws;                 // 8 KB scratch

  hipLaunchKernelGGL(conv_x,   dim3(4096),    dim3(256), 0, stream, x, embed, halfe2, out);
  hipLaunchKernelGGL(vq_main,  dim3((MMM/TMQ)*KSPLIT), dim3(256), 0, stream, halfe2, out);
  hipLaunchKernelGGL(vq_merge, dim3(MMM/256), dim3(256), 0, stream, out);
  hipLaunchKernelGGL(vq_prep,  dim3(256),     dim3(256), 0, stream, x, out);
  hipLaunchKernelGGL(vq_refine,dim3(16, CAPF/64), dim3(256), 0, stream, embed, halfe2, out);
  hipLaunchKernelGGL(vq_apply, dim3(CAPF/256),dim3(256), 0, stream, out);
  hipLaunchKernelGGL(vq_gather,dim3(MMM/128), dim3(256), 0, stream, embed, out);
}